// Round 11
// baseline (102.329 us; speedup 1.0000x reference)
//
// v10-r11: byte-equivalent resubmit of R10 after broker failure (audit clean).
#include <hip/hip_runtime.h>

typedef _Float16 half_t;
typedef _Float16 h2 __attribute__((ext_vector_type(2)));
typedef unsigned int uint32;

#define K_ 100
#define F_ 128
#define E_ 200

#if defined(__has_builtin)
#if __has_builtin(__builtin_amdgcn_fdot2)
#define FDOT2(a,b,c) __builtin_amdgcn_fdot2((a),(b),(c),false)
#endif
#endif
#ifndef FDOT2
#define FDOT2(a,b,c) fmaf((float)(a).y,(float)(b).y, fmaf((float)(a).x,(float)(b).x,(c)))
#endif

__device__ __forceinline__ h2 bch2(uint32 u){ return __builtin_bit_cast(h2,u); }
__device__ __forceinline__ uint32 pkh2(float a, float b){
  h2 p; p.x=(half_t)a; p.y=(half_t)b; return __builtin_bit_cast(uint32,p);
}

// ws layout (uint words):
//  Lh[6400][100] @0 ; Rh[6400][100] @640000 ; ah2[100] @1280000
//  AL[6400] f32 @1280128 ; AR[6400] f32 @1286528 ; XJ[64*50][128] @1292928
#define LH_OFF 0
#define RH_OFF 640000
#define AH_OFF 1280000
#define AL_OFF 1280128
#define AR_OFF 1286528
#define XJ_OFF 1292928

// K1: projection. Thread t<100 computes BOTH L and R for e-pair t —
// xsh broadcast read once serves 4 accumulator sets (half the LDS-pipe
// traffic of the 200-thread version). FDOT2 order per accumulator identical.
__global__ __launch_bounds__(256) void k_proj(
    const float* __restrict__ x, const float* __restrict__ W,
    const float* __restrict__ bvec, const float* __restrict__ avec,
    uint32* __restrict__ ws)
{
  const int t  = threadIdx.x;
  const int r0 = (int)blockIdx.x * 10;

  __shared__ __align__(16) uint32 xsh[10 * 64];   // x rows, h2 f-pairs
  __shared__ float red[20][100];                  // al/ar partials  8 KB
  __shared__ float red2[20 * 10];                 // stage-1 sums    0.8 KB

  for (int u = t; u < 640; u += 256) {
    int row = u >> 6, f2 = u & 63;
    const float* xp = x + (size_t)(r0 + row) * F_ + 2 * f2;
    xsh[row * 64 + f2] = pkh2(xp[0], xp[1]);
  }
  if (blockIdx.x == 0 && t < 100)
    ws[AH_OFF + t] = pkh2(avec[2*t], avec[2*t+1]);   // for k_main
  __syncthreads();

  // XJ: pack (x[2jp][f], x[2jp+1][f]) for this block's 5 j-pairs.
  for (int u = t; u < 640; u += 256) {
    int f = u & 127, lp = u >> 7;
    uint32 u0 = xsh[(2*lp)     * 64 + (f >> 1)];
    uint32 u1 = xsh[(2*lp + 1) * 64 + (f >> 1)];
    int sh = (f & 1) * 16;
    ws[XJ_OFF + (size_t)(r0/2 + lp) * 128 + f] =
        ((u0 >> sh) & 0xffffu) | (((u1 >> sh) & 0xffffu) << 16);
  }

  if (t < 100) {
    const int e2 = t;
    const float* WpL = W + 2 * e2;                       // rows 0..127
    const float* WpR = W + (size_t)128 * E_ + 2 * e2;    // rows 128..255

    float aL0[10], aL1[10], aR0[10], aR1[10];
    #pragma unroll
    for (int r = 0; r < 10; ++r) { aL0[r]=0.f; aL1[r]=0.f; aR0[r]=0.f; aR1[r]=0.f; }

    for (int q = 0; q < 16; ++q) {
      uint32 wL0[4], wL1[4], wR0[4], wR1[4];
      #pragma unroll
      for (int fp = 0; fp < 4; ++fp) {          // per-wave contiguous row reads
        const float* pL = WpL + (size_t)(8*q + 2*fp) * E_;
        float2 Av = *(const float2*)pL;
        float2 Bv = *(const float2*)(pL + E_);
        wL0[fp] = pkh2(Av.x, Bv.x);
        wL1[fp] = pkh2(Av.y, Bv.y);
        const float* pR = WpR + (size_t)(8*q + 2*fp) * E_;
        float2 Cv = *(const float2*)pR;
        float2 Dv = *(const float2*)(pR + E_);
        wR0[fp] = pkh2(Cv.x, Dv.x);
        wR1[fp] = pkh2(Cv.y, Dv.y);
      }
      #pragma unroll
      for (int r = 0; r < 10; ++r) {
        uint4 xq = *(const uint4*)(xsh + r * 64 + 4 * q);   // uniform -> broadcast
        aL0[r] = FDOT2(bch2(xq.x), bch2(wL0[0]), aL0[r]);
        aL0[r] = FDOT2(bch2(xq.y), bch2(wL0[1]), aL0[r]);
        aL0[r] = FDOT2(bch2(xq.z), bch2(wL0[2]), aL0[r]);
        aL0[r] = FDOT2(bch2(xq.w), bch2(wL0[3]), aL0[r]);
        aL1[r] = FDOT2(bch2(xq.x), bch2(wL1[0]), aL1[r]);
        aL1[r] = FDOT2(bch2(xq.y), bch2(wL1[1]), aL1[r]);
        aL1[r] = FDOT2(bch2(xq.z), bch2(wL1[2]), aL1[r]);
        aL1[r] = FDOT2(bch2(xq.w), bch2(wL1[3]), aL1[r]);
        aR0[r] = FDOT2(bch2(xq.x), bch2(wR0[0]), aR0[r]);
        aR0[r] = FDOT2(bch2(xq.y), bch2(wR0[1]), aR0[r]);
        aR0[r] = FDOT2(bch2(xq.z), bch2(wR0[2]), aR0[r]);
        aR0[r] = FDOT2(bch2(xq.w), bch2(wR0[3]), aR0[r]);
        aR1[r] = FDOT2(bch2(xq.x), bch2(wR1[0]), aR1[r]);
        aR1[r] = FDOT2(bch2(xq.y), bch2(wR1[1]), aR1[r]);
        aR1[r] = FDOT2(bch2(xq.z), bch2(wR1[2]), aR1[r]);
        aR1[r] = FDOT2(bch2(xq.w), bch2(wR1[3]), aR1[r]);
      }
    }
    {
      float b0 = bvec[2 * e2], b1 = bvec[2 * e2 + 1];
      #pragma unroll
      for (int r = 0; r < 10; ++r) { aR0[r] += b0; aR1[r] += b1; }
    }
    h2 a2 = bch2(pkh2(avec[2*e2], avec[2*e2+1]));
    #pragma unroll
    for (int r = 0; r < 10; ++r) {
      uint32 prL = pkh2(aL0[r], aL1[r]);
      ws[LH_OFF + (size_t)(r0 + r) * 100 + e2] = prL;
      red[r][e2] = FDOT2(a2, bch2(prL), 0.f);
      uint32 prR = pkh2(aR0[r], aR1[r]);
      ws[RH_OFF + (size_t)(r0 + r) * 100 + e2] = prR;
      red[10 + r][e2] = FDOT2(a2, bch2(prR), 0.f);
    }
  }
  __syncthreads();

  // AL/AR reduction, two stages: 200 threads x 10 elems, then 20 x 10.
  if (t < 200) {
    int rr = t / 10, seg = t % 10;
    const float* rp = red[rr] + seg * 10;
    float s = 0.f;
    #pragma unroll
    for (int k = 0; k < 10; ++k) s += rp[k];
    red2[rr * 10 + seg] = s;
  }
  __syncthreads();
  if (t < 20) {
    float s = 0.f;
    #pragma unroll
    for (int k = 0; k < 10; ++k) s += red2[t * 10 + k];
    float* dstf = (float*)(ws + (t >= 10 ? AR_OFF : AL_OFF));
    dstf[r0 + (t % 10)] = s;
  }
}

// one e-uint (2 e's) into one accumulator: nonlinear term only
#define STEPA(A_, lu, au, ru)                                              \
  do {                                                                     \
    h2 mm = __builtin_elementwise_min(bch2(lu) + bch2(ru), z2);            \
    A_ = FDOT2(bch2(au), mm, A_);                                          \
  } while (0)

// K2: LDS-staged pair sweep (R9 structure). PV reads att2 via b128
// (rows padded to 52 uints, 12 chunks + uint2 tail) — 65 LDS reads/thread
// instead of 250 b32. jp accumulation order per z[m] unchanged.
__global__ __launch_bounds__(256) void k_main(
    const float* __restrict__ x, const float* __restrict__ bias,
    const uint32* __restrict__ ws, float* __restrict__ out)
{
  const int t  = threadIdx.x;
  const int i0 = (int)blockIdx.x * 10;
  const int b  = (int)blockIdx.y;

  __shared__ __align__(16) uint32 Rsh[100 * 100];   // 40 KB
  __shared__ __align__(16) uint32 Lsh[10 * 100];    //  4 KB
  __shared__ float  att[10 * 100];                  //  4 KB
  __shared__ __align__(16) uint32 att2[10 * 52];    //  2.1 KB (row pad 52)
  __shared__ float  scratch[512];                   //  2 KB (2 planes)
  __shared__ float  rowmax[10], rowinv[10];

  const bool act = (t < 250);
  const int iq = act ? (t % 5) : 0;    // i-pair: rows 2iq, 2iq+1
  const int tj = act ? (t / 5) : 0;    // 0..49;  j = tj, tj+50

  // ---- stage R (100 rows) and L (10 rows): pure contiguous copies ----
  {
    const uint4* Rb4 = (const uint4*)(ws + RH_OFF + (size_t)b * K_ * 100);
    for (int u = t; u < 2500; u += 256)
      *(uint4*)(&Rsh[u * 4]) = Rb4[u];
    const uint4* Lb4 = (const uint4*)(ws + LH_OFF + (size_t)(b * K_ + i0) * 100);
    if (t < 250)
      *(uint4*)(&Lsh[t * 4]) = Lb4[t];
  }
  __syncthreads();

  float acc[2][2] = {{0.f,0.f},{0.f,0.f}};
  h2 z2; z2.x = (half_t)0; z2.y = (half_t)0;

  if (act) {
    const uint4* Ag  = (const uint4*)(ws + AH_OFF);   // wave-uniform -> s_load
    const uint32* Lp0 = Lsh + (2*iq)     * 100;
    const uint32* Lp1 = Lsh + (2*iq + 1) * 100;
    const uint32* Rp0 = Rsh + tj * 100;
    const uint32* Rp1 = Rsh + (tj + 50) * 100;
    #pragma unroll 5
    for (int q = 0; q < 25; ++q) {
      uint4 Aq  = Ag[q];
      uint4 L0q = *(const uint4*)(Lp0 + 4*q);
      uint4 L1q = *(const uint4*)(Lp1 + 4*q);
      uint4 R0q = *(const uint4*)(Rp0 + 4*q);
      uint4 R1q = *(const uint4*)(Rp1 + 4*q);
      STEPA(acc[0][0], L0q.x, Aq.x, R0q.x); STEPA(acc[0][1], L0q.x, Aq.x, R1q.x);
      STEPA(acc[1][0], L1q.x, Aq.x, R0q.x); STEPA(acc[1][1], L1q.x, Aq.x, R1q.x);
      STEPA(acc[0][0], L0q.y, Aq.y, R0q.y); STEPA(acc[0][1], L0q.y, Aq.y, R1q.y);
      STEPA(acc[1][0], L1q.y, Aq.y, R0q.y); STEPA(acc[1][1], L1q.y, Aq.y, R1q.y);
      STEPA(acc[0][0], L0q.z, Aq.z, R0q.z); STEPA(acc[0][1], L0q.z, Aq.z, R1q.z);
      STEPA(acc[1][0], L1q.z, Aq.z, R0q.z); STEPA(acc[1][1], L1q.z, Aq.z, R1q.z);
      STEPA(acc[0][0], L0q.w, Aq.w, R0q.w); STEPA(acc[0][1], L0q.w, Aq.w, R1q.w);
      STEPA(acc[1][0], L1q.w, Aq.w, R0q.w); STEPA(acc[1][1], L1q.w, Aq.w, R1q.w);
    }
  }

  float v[2][2];
  if (act) {
    const float* ALf = (const float*)(ws + AL_OFF);
    const float* ARf = (const float*)(ws + AR_OFF);
    float al0 = ALf[b*K_ + i0 + 2*iq];
    float al1 = ALf[b*K_ + i0 + 2*iq + 1];
    #pragma unroll
    for (int s = 0; s < 2; ++s) {
      int j = tj + 50*s;
      float arj = ARf[b*K_ + j];
      float lv0 = al0 + arj + bias[(i0 + 2*iq)*K_ + j]     - 0.8f*acc[0][s];
      float lv1 = al1 + arj + bias[(i0 + 2*iq + 1)*K_ + j] - 0.8f*acc[1][s];
      v[0][s] = fminf(fmaxf(lv0, -30000.f), 30000.f);
      v[1][s] = fminf(fmaxf(lv1, -30000.f), 30000.f);
    }
  }

  {
    float m0 = -3.0e38f, m1 = -3.0e38f;
    if (act) {
      m0 = fmaxf(v[0][0], v[0][1]);
      m1 = fmaxf(v[1][0], v[1][1]);
    }
    scratch[t] = m0; scratch[256 + t] = m1;
    __syncthreads();
    if (t < 10) {                      // row t = 2*(t>>1) + (t&1)
      int p = t & 1, iqr = t >> 1;
      const float* sp = scratch + p*256 + iqr;
      float mm = sp[0];
      for (int k = 1; k < 50; ++k) mm = fmaxf(mm, sp[5*k]);
      rowmax[t] = mm;
    }
    __syncthreads();
    float e0 = 0.f, e1 = 0.f;
    if (act) {
      float ma = rowmax[2*iq], mb = rowmax[2*iq + 1];
      e0 = __expf(v[0][0] - ma) + __expf(v[0][1] - ma);
      e1 = __expf(v[1][0] - mb) + __expf(v[1][1] - mb);
    }
    scratch[t] = e0; scratch[256 + t] = e1;
    __syncthreads();
    if (t < 10) {
      int p = t & 1, iqr = t >> 1;
      const float* sp = scratch + p*256 + iqr;
      float s2 = 0.f;
      for (int k = 0; k < 50; ++k) s2 += sp[5*k];
      rowinv[t] = 1.f / s2;
    }
    __syncthreads();
  }
  if (act) {
    #pragma unroll
    for (int p = 0; p < 2; ++p) {
      int row = 2*iq + p;
      float m = rowmax[row], inv = rowinv[row];
      att[row*K_ + tj]      = __expf(v[p][0] - m) * inv;
      att[row*K_ + tj + 50] = __expf(v[p][1] - m) * inv;
    }
  }
  __syncthreads();
  for (int u = t; u < 500; u += 256) {
    int i = u / 50, jp = u - i*50;
    att2[i*52 + jp] = pkh2(att[i*K_ + 2*jp], att[i*K_ + 2*jp + 1]);
  }
  __syncthreads();

  {
    const int f = t & 127, ig = t >> 7;        // ig in {0,1}: rows ig*5+m
    const uint32* XJ = ws + XJ_OFF + (size_t)(b*50) * 128 + f;
    const uint32* a2p = att2 + (ig * 5) * 52;
    float z[5] = {0.f, 0.f, 0.f, 0.f, 0.f};

#define PVK(kk, comp)                                       \
    { h2 xv = bch2(XJ[(4*c + kk) * 128]);                   \
      z[0] = FDOT2(bch2(p0.comp), xv, z[0]);                \
      z[1] = FDOT2(bch2(p1.comp), xv, z[1]);                \
      z[2] = FDOT2(bch2(p2.comp), xv, z[2]);                \
      z[3] = FDOT2(bch2(p3.comp), xv, z[3]);                \
      z[4] = FDOT2(bch2(p4.comp), xv, z[4]); }

    for (int c = 0; c < 12; ++c) {             // jp = 4c .. 4c+3  (0..47)
      uint4 p0 = *(const uint4*)(a2p + 0*52 + 4*c);
      uint4 p1 = *(const uint4*)(a2p + 1*52 + 4*c);
      uint4 p2 = *(const uint4*)(a2p + 2*52 + 4*c);
      uint4 p3 = *(const uint4*)(a2p + 3*52 + 4*c);
      uint4 p4 = *(const uint4*)(a2p + 4*52 + 4*c);
      PVK(0, x) PVK(1, y) PVK(2, z) PVK(3, w)
    }
#undef PVK
    {                                          // tail jp = 48, 49
      uint2 q0 = *(const uint2*)(a2p + 0*52 + 48);
      uint2 q1 = *(const uint2*)(a2p + 1*52 + 48);
      uint2 q2 = *(const uint2*)(a2p + 2*52 + 48);
      uint2 q3 = *(const uint2*)(a2p + 3*52 + 48);
      uint2 q4 = *(const uint2*)(a2p + 4*52 + 48);
      h2 xv48 = bch2(XJ[48 * 128]);
      h2 xv49 = bch2(XJ[49 * 128]);
      z[0] = FDOT2(bch2(q0.x), xv48, z[0]); z[0] = FDOT2(bch2(q0.y), xv49, z[0]);
      z[1] = FDOT2(bch2(q1.x), xv48, z[1]); z[1] = FDOT2(bch2(q1.y), xv49, z[1]);
      z[2] = FDOT2(bch2(q2.x), xv48, z[2]); z[2] = FDOT2(bch2(q2.y), xv49, z[2]);
      z[3] = FDOT2(bch2(q3.x), xv48, z[3]); z[3] = FDOT2(bch2(q3.y), xv49, z[3]);
      z[4] = FDOT2(bch2(q4.x), xv48, z[4]); z[4] = FDOT2(bch2(q4.y), xv49, z[4]);
    }

    #pragma unroll
    for (int m = 0; m < 5; ++m) {
      int i = ig*5 + m;
      out[(size_t)(b*K_ + i0 + i)*F_ + f] = 1.f / (1.f + __expf(-z[m]));
    }
  }
}

extern "C" void kernel_launch(void* const* d_in, const int* in_sizes, int n_in,
                              void* d_out, int out_size, void* d_ws, size_t ws_size,
                              hipStream_t stream)
{
  const float* x    = (const float*)d_in[0];   // (64,100,128) f32
  const float* W    = (const float*)d_in[1];   // (256,200) f32
  const float* bvec = (const float*)d_in[2];   // (200,) f32
  const float* avec = (const float*)d_in[3];   // (200,) f32
  const float* bias = (const float*)d_in[4];   // (100,100) f32
  float* out  = (float*)d_out;                 // (64,100,128) f32
  uint32* ws  = (uint32*)d_ws;                 // ~6.8 MB used

  k_proj<<<dim3(640),    dim3(256), 0, stream>>>(x, W, bvec, avec, ws);
  k_main<<<dim3(10, 64), dim3(256), 0, stream>>>(x, bias, ws, out);
}

// Round 12
// 96.568 us; speedup vs baseline: 1.0597x; 1.0597x over previous
//
#include <hip/hip_runtime.h>

typedef _Float16 half_t;
typedef _Float16 h2 __attribute__((ext_vector_type(2)));
typedef unsigned int uint32;

#define K_ 100
#define F_ 128
#define E_ 200

#if defined(__has_builtin)
#if __has_builtin(__builtin_amdgcn_fdot2)
#define FDOT2(a,b,c) __builtin_amdgcn_fdot2((a),(b),(c),false)
#endif
#endif
#ifndef FDOT2
#define FDOT2(a,b,c) fmaf((float)(a).y,(float)(b).y, fmaf((float)(a).x,(float)(b).x,(c)))
#endif

__device__ __forceinline__ h2 bch2(uint32 u){ return __builtin_bit_cast(h2,u); }
__device__ __forceinline__ uint32 pkh2(float a, float b){
  h2 p; p.x=(half_t)a; p.y=(half_t)b; return __builtin_bit_cast(uint32,p);
}

// ws layout (uint words):
//  Lh[6400][100] @0 ; Rh[6400][100] @640000 ; ah2[100] @1280000
//  AL[6400] f32 @1280128 ; AR[6400] f32 @1286528 ; XJ[64*50][128] @1292928
#define LH_OFF 0
#define RH_OFF 640000
#define AH_OFF 1280000
#define AL_OFF 1280128
#define AR_OFF 1286528
#define XJ_OFF 1292928

// K1: projection — EXACT R9-measured version (200 threads, W direct from
// global, parallel AL/AR tail). The R10 100-thread rewrite regressed
// (parallelism-bound phase); reverted.
__global__ __launch_bounds__(256) void k_proj(
    const float* __restrict__ x, const float* __restrict__ W,
    const float* __restrict__ bvec, const float* __restrict__ avec,
    uint32* __restrict__ ws)
{
  const int t  = threadIdx.x;
  const int r0 = (int)blockIdx.x * 10;

  __shared__ __align__(16) uint32 xsh[10 * 64];   // x rows, h2 f-pairs
  __shared__ float red[20][100];                  // al/ar partials  8 KB
  __shared__ float red2[20 * 10];                 // stage-1 sums    0.8 KB

  for (int u = t; u < 640; u += 256) {
    int row = u >> 6, f2 = u & 63;
    const float* xp = x + (size_t)(r0 + row) * F_ + 2 * f2;
    xsh[row * 64 + f2] = pkh2(xp[0], xp[1]);
  }
  if (blockIdx.x == 0 && t < 100)
    ws[AH_OFF + t] = pkh2(avec[2*t], avec[2*t+1]);   // for k_main
  __syncthreads();

  // XJ: pack (x[2jp][f], x[2jp+1][f]) for this block's 5 j-pairs.
  for (int u = t; u < 640; u += 256) {
    int f = u & 127, lp = u >> 7;
    uint32 u0 = xsh[(2*lp)     * 64 + (f >> 1)];
    uint32 u1 = xsh[(2*lp + 1) * 64 + (f >> 1)];
    int sh = (f & 1) * 16;
    ws[XJ_OFF + (size_t)(r0/2 + lp) * 128 + f] =
        ((u0 >> sh) & 0xffffu) | (((u1 >> sh) & 0xffffu) << 16);
  }

  if (t < 200) {
    const bool isR = (t >= 100);
    const int e2 = isR ? (t - 100) : t;          // output uint index within row
    const float* Wp = W + (size_t)(isR ? 128 : 0) * E_ + 2 * e2;

    float acc0[10], acc1[10];
    #pragma unroll
    for (int r = 0; r < 10; ++r) { acc0[r] = 0.f; acc1[r] = 0.f; }

    #pragma unroll
    for (int q = 0; q < 16; ++q) {
      uint32 w0u[4], w1u[4];
      #pragma unroll
      for (int fp = 0; fp < 4; ++fp) {           // per-wave contiguous row reads
        const float* p0 = Wp + (size_t)(8*q + 2*fp) * E_;
        float2 Av = *(const float2*)p0;          // row f  : cols 2e2,2e2+1
        float2 Bv = *(const float2*)(p0 + E_);   // row f+1: cols 2e2,2e2+1
        w0u[fp] = pkh2(Av.x, Bv.x);
        w1u[fp] = pkh2(Av.y, Bv.y);
      }
      #pragma unroll
      for (int r = 0; r < 10; ++r) {
        uint4 xq = *(const uint4*)(xsh + r * 64 + 4 * q);   // uniform -> broadcast
        acc0[r] = FDOT2(bch2(xq.x), bch2(w0u[0]), acc0[r]);
        acc0[r] = FDOT2(bch2(xq.y), bch2(w0u[1]), acc0[r]);
        acc0[r] = FDOT2(bch2(xq.z), bch2(w0u[2]), acc0[r]);
        acc0[r] = FDOT2(bch2(xq.w), bch2(w0u[3]), acc0[r]);
        acc1[r] = FDOT2(bch2(xq.x), bch2(w1u[0]), acc1[r]);
        acc1[r] = FDOT2(bch2(xq.y), bch2(w1u[1]), acc1[r]);
        acc1[r] = FDOT2(bch2(xq.z), bch2(w1u[2]), acc1[r]);
        acc1[r] = FDOT2(bch2(xq.w), bch2(w1u[3]), acc1[r]);
      }
    }
    if (isR) {
      float b0 = bvec[2 * e2], b1 = bvec[2 * e2 + 1];
      #pragma unroll
      for (int r = 0; r < 10; ++r) { acc0[r] += b0; acc1[r] += b1; }
    }
    h2 a2 = bch2(pkh2(avec[2*e2], avec[2*e2+1]));
    uint32* dst = ws + (isR ? RH_OFF : LH_OFF);
    #pragma unroll
    for (int r = 0; r < 10; ++r) {
      uint32 pr = pkh2(acc0[r], acc1[r]);
      dst[(size_t)(r0 + r) * 100 + e2] = pr;
      red[(isR ? 10 : 0) + r][e2] = FDOT2(a2, bch2(pr), 0.f);
    }
  }
  __syncthreads();

  // AL/AR reduction, two stages: 200 threads x 10 elems, then 20 x 10.
  if (t < 200) {
    int rr = t / 10, seg = t % 10;
    const float* rp = red[rr] + seg * 10;
    float s = 0.f;
    #pragma unroll
    for (int k = 0; k < 10; ++k) s += rp[k];
    red2[rr * 10 + seg] = s;
  }
  __syncthreads();
  if (t < 20) {
    float s = 0.f;
    #pragma unroll
    for (int k = 0; k < 10; ++k) s += red2[t * 10 + k];
    float* dstf = (float*)(ws + (t >= 10 ? AR_OFF : AL_OFF));
    dstf[r0 + (t % 10)] = s;
  }
}

// one e-uint (2 e's) into one accumulator: nonlinear term only
#define STEPA(A_, lu, au, ru)                                              \
  do {                                                                     \
    h2 mm = __builtin_elementwise_min(bch2(lu) + bch2(ru), z2);            \
    A_ = FDOT2(bch2(au), mm, A_);                                          \
  } while (0)

// K2: R9 sweep structure + isolated PV change: att2 rows padded to 52 uints,
// PV reads via b128 (12 chunks + uint2 tail) — 65 LDS reads/thread vs 250.
// jp accumulation order per z[m] unchanged (bit-identical).
__global__ __launch_bounds__(256) void k_main(
    const float* __restrict__ x, const float* __restrict__ bias,
    const uint32* __restrict__ ws, float* __restrict__ out)
{
  const int t  = threadIdx.x;
  const int i0 = (int)blockIdx.x * 10;
  const int b  = (int)blockIdx.y;

  __shared__ __align__(16) uint32 Rsh[100 * 100];   // 40 KB
  __shared__ __align__(16) uint32 Lsh[10 * 100];    //  4 KB
  __shared__ float  att[10 * 100];                  //  4 KB
  __shared__ __align__(16) uint32 att2[10 * 52];    //  2.1 KB (row pad 52)
  __shared__ float  scratch[512];                   //  2 KB (2 planes)
  __shared__ float  rowmax[10], rowinv[10];

  const bool act = (t < 250);
  const int iq = act ? (t % 5) : 0;    // i-pair: rows 2iq, 2iq+1
  const int tj = act ? (t / 5) : 0;    // 0..49;  j = tj, tj+50

  // ---- stage R (100 rows) and L (10 rows): pure contiguous copies ----
  {
    const uint4* Rb4 = (const uint4*)(ws + RH_OFF + (size_t)b * K_ * 100);
    for (int u = t; u < 2500; u += 256)
      *(uint4*)(&Rsh[u * 4]) = Rb4[u];
    const uint4* Lb4 = (const uint4*)(ws + LH_OFF + (size_t)(b * K_ + i0) * 100);
    if (t < 250)
      *(uint4*)(&Lsh[t * 4]) = Lb4[t];
  }
  __syncthreads();

  float acc[2][2] = {{0.f,0.f},{0.f,0.f}};
  h2 z2; z2.x = (half_t)0; z2.y = (half_t)0;

  if (act) {
    const uint4* Ag  = (const uint4*)(ws + AH_OFF);   // wave-uniform -> s_load
    const uint32* Lp0 = Lsh + (2*iq)     * 100;
    const uint32* Lp1 = Lsh + (2*iq + 1) * 100;
    const uint32* Rp0 = Rsh + tj * 100;
    const uint32* Rp1 = Rsh + (tj + 50) * 100;
    #pragma unroll 5
    for (int q = 0; q < 25; ++q) {
      uint4 Aq  = Ag[q];
      uint4 L0q = *(const uint4*)(Lp0 + 4*q);
      uint4 L1q = *(const uint4*)(Lp1 + 4*q);
      uint4 R0q = *(const uint4*)(Rp0 + 4*q);
      uint4 R1q = *(const uint4*)(Rp1 + 4*q);
      STEPA(acc[0][0], L0q.x, Aq.x, R0q.x); STEPA(acc[0][1], L0q.x, Aq.x, R1q.x);
      STEPA(acc[1][0], L1q.x, Aq.x, R0q.x); STEPA(acc[1][1], L1q.x, Aq.x, R1q.x);
      STEPA(acc[0][0], L0q.y, Aq.y, R0q.y); STEPA(acc[0][1], L0q.y, Aq.y, R1q.y);
      STEPA(acc[1][0], L1q.y, Aq.y, R0q.y); STEPA(acc[1][1], L1q.y, Aq.y, R1q.y);
      STEPA(acc[0][0], L0q.z, Aq.z, R0q.z); STEPA(acc[0][1], L0q.z, Aq.z, R1q.z);
      STEPA(acc[1][0], L1q.z, Aq.z, R0q.z); STEPA(acc[1][1], L1q.z, Aq.z, R1q.z);
      STEPA(acc[0][0], L0q.w, Aq.w, R0q.w); STEPA(acc[0][1], L0q.w, Aq.w, R1q.w);
      STEPA(acc[1][0], L1q.w, Aq.w, R0q.w); STEPA(acc[1][1], L1q.w, Aq.w, R1q.w);
    }
  }

  float v[2][2];
  if (act) {
    const float* ALf = (const float*)(ws + AL_OFF);
    const float* ARf = (const float*)(ws + AR_OFF);
    float al0 = ALf[b*K_ + i0 + 2*iq];
    float al1 = ALf[b*K_ + i0 + 2*iq + 1];
    #pragma unroll
    for (int s = 0; s < 2; ++s) {
      int j = tj + 50*s;
      float arj = ARf[b*K_ + j];
      float lv0 = al0 + arj + bias[(i0 + 2*iq)*K_ + j]     - 0.8f*acc[0][s];
      float lv1 = al1 + arj + bias[(i0 + 2*iq + 1)*K_ + j] - 0.8f*acc[1][s];
      v[0][s] = fminf(fmaxf(lv0, -30000.f), 30000.f);
      v[1][s] = fminf(fmaxf(lv1, -30000.f), 30000.f);
    }
  }

  {
    float m0 = -3.0e38f, m1 = -3.0e38f;
    if (act) {
      m0 = fmaxf(v[0][0], v[0][1]);
      m1 = fmaxf(v[1][0], v[1][1]);
    }
    scratch[t] = m0; scratch[256 + t] = m1;
    __syncthreads();
    if (t < 10) {                      // row t = 2*(t>>1) + (t&1)
      int p = t & 1, iqr = t >> 1;
      const float* sp = scratch + p*256 + iqr;
      float mm = sp[0];
      for (int k = 1; k < 50; ++k) mm = fmaxf(mm, sp[5*k]);
      rowmax[t] = mm;
    }
    __syncthreads();
    float e0 = 0.f, e1 = 0.f;
    if (act) {
      float ma = rowmax[2*iq], mb = rowmax[2*iq + 1];
      e0 = __expf(v[0][0] - ma) + __expf(v[0][1] - ma);
      e1 = __expf(v[1][0] - mb) + __expf(v[1][1] - mb);
    }
    scratch[t] = e0; scratch[256 + t] = e1;
    __syncthreads();
    if (t < 10) {
      int p = t & 1, iqr = t >> 1;
      const float* sp = scratch + p*256 + iqr;
      float s2 = 0.f;
      for (int k = 0; k < 50; ++k) s2 += sp[5*k];
      rowinv[t] = 1.f / s2;
    }
    __syncthreads();
  }
  if (act) {
    #pragma unroll
    for (int p = 0; p < 2; ++p) {
      int row = 2*iq + p;
      float m = rowmax[row], inv = rowinv[row];
      att[row*K_ + tj]      = __expf(v[p][0] - m) * inv;
      att[row*K_ + tj + 50] = __expf(v[p][1] - m) * inv;
    }
  }
  __syncthreads();
  for (int u = t; u < 500; u += 256) {
    int i = u / 50, jp = u - i*50;
    att2[i*52 + jp] = pkh2(att[i*K_ + 2*jp], att[i*K_ + 2*jp + 1]);
  }
  __syncthreads();

  {
    const int f = t & 127, ig = t >> 7;        // ig in {0,1}: rows ig*5+m
    const uint32* XJ = ws + XJ_OFF + (size_t)(b*50) * 128 + f;
    const uint32* a2p = att2 + (ig * 5) * 52;
    float z[5] = {0.f, 0.f, 0.f, 0.f, 0.f};

#define PVK(kk, comp)                                       \
    { h2 xv = bch2(XJ[(4*c + kk) * 128]);                   \
      z[0] = FDOT2(bch2(p0.comp), xv, z[0]);                \
      z[1] = FDOT2(bch2(p1.comp), xv, z[1]);                \
      z[2] = FDOT2(bch2(p2.comp), xv, z[2]);                \
      z[3] = FDOT2(bch2(p3.comp), xv, z[3]);                \
      z[4] = FDOT2(bch2(p4.comp), xv, z[4]); }

    for (int c = 0; c < 12; ++c) {             // jp = 4c .. 4c+3  (0..47)
      uint4 p0 = *(const uint4*)(a2p + 0*52 + 4*c);
      uint4 p1 = *(const uint4*)(a2p + 1*52 + 4*c);
      uint4 p2 = *(const uint4*)(a2p + 2*52 + 4*c);
      uint4 p3 = *(const uint4*)(a2p + 3*52 + 4*c);
      uint4 p4 = *(const uint4*)(a2p + 4*52 + 4*c);
      PVK(0, x) PVK(1, y) PVK(2, z) PVK(3, w)
    }
#undef PVK
    {                                          // tail jp = 48, 49
      uint2 q0 = *(const uint2*)(a2p + 0*52 + 48);
      uint2 q1 = *(const uint2*)(a2p + 1*52 + 48);
      uint2 q2 = *(const uint2*)(a2p + 2*52 + 48);
      uint2 q3 = *(const uint2*)(a2p + 3*52 + 48);
      uint2 q4 = *(const uint2*)(a2p + 4*52 + 48);
      h2 xv48 = bch2(XJ[48 * 128]);
      h2 xv49 = bch2(XJ[49 * 128]);
      z[0] = FDOT2(bch2(q0.x), xv48, z[0]); z[0] = FDOT2(bch2(q0.y), xv49, z[0]);
      z[1] = FDOT2(bch2(q1.x), xv48, z[1]); z[1] = FDOT2(bch2(q1.y), xv49, z[1]);
      z[2] = FDOT2(bch2(q2.x), xv48, z[2]); z[2] = FDOT2(bch2(q2.y), xv49, z[2]);
      z[3] = FDOT2(bch2(q3.x), xv48, z[3]); z[3] = FDOT2(bch2(q3.y), xv49, z[3]);
      z[4] = FDOT2(bch2(q4.x), xv48, z[4]); z[4] = FDOT2(bch2(q4.y), xv49, z[4]);
    }

    #pragma unroll
    for (int m = 0; m < 5; ++m) {
      int i = ig*5 + m;
      out[(size_t)(b*K_ + i0 + i)*F_ + f] = 1.f / (1.f + __expf(-z[m]));
    }
  }
}

extern "C" void kernel_launch(void* const* d_in, const int* in_sizes, int n_in,
                              void* d_out, int out_size, void* d_ws, size_t ws_size,
                              hipStream_t stream)
{
  const float* x    = (const float*)d_in[0];   // (64,100,128) f32
  const float* W    = (const float*)d_in[1];   // (256,200) f32
  const float* bvec = (const float*)d_in[2];   // (200,) f32
  const float* avec = (const float*)d_in[3];   // (200,) f32
  const float* bias = (const float*)d_in[4];   // (100,100) f32
  float* out  = (float*)d_out;                 // (64,100,128) f32
  uint32* ws  = (uint32*)d_ws;                 // ~6.8 MB used

  k_proj<<<dim3(640),    dim3(256), 0, stream>>>(x, W, bvec, avec, ws);
  k_main<<<dim3(10, 64), dim3(256), 0, stream>>>(x, bias, ws, out);
}